// Round 11
// baseline (421.876 us; speedup 1.0000x reference)
//
#include <hip/hip_runtime.h>
#include <hip/hip_bf16.h>

// AngleOrientedConv: per space k (S=4):
//   a  = feat @ W[k][:128,:];  bp = feat @ W[k][128:,:] + b[k]
//   e  = sum_j tanh(a[src][j] + bp[dst][j]) * w[k][j]
//   segment softmax over dst; out[:, k*128:(k+1)*128] = sum alpha * feat[src]
//
// Round 11: persistent grid-stride fused kernel (2048 blocks = 32 waves/CU),
// per-space constants hoisted out of the node loop, space<->XCD affinity via
// s = bid % S. No prefetch (hurt in r7 and r10). Rest = round-8 pipeline.

#define F 128

typedef __attribute__((ext_vector_type(8))) short short8v;   // 8 bf16
typedef __attribute__((ext_vector_type(4))) float f32x4;
typedef __attribute__((ext_vector_type(2))) float f32x2;

__device__ __forceinline__ unsigned f2bf(float x) {  // round-to-nearest-even
    unsigned u = __float_as_uint(x);
    unsigned r = ((u >> 16) & 1u) + 0x7fffu;
    return (u + r) >> 16;
}
__device__ __forceinline__ float bf_lo(unsigned v) { return __uint_as_float(v << 16); }
__device__ __forceinline__ float bf_hi(unsigned v) { return __uint_as_float(v & 0xffff0000u); }

// ---------------- feat -> bf16 (once) ----------------
__global__ __launch_bounds__(256) void cvt_feat_kernel(
    const float* __restrict__ feat, unsigned* __restrict__ feat16, int n4)
{
    for (int i = blockIdx.x * 256 + threadIdx.x; i < n4; i += gridDim.x * 256) {
        float4 v = *(const float4*)(feat + (size_t)i * 4);
        unsigned lo = f2bf(v.x) | (f2bf(v.y) << 16);
        unsigned hi = f2bf(v.z) | (f2bf(v.w) << 16);
        *(uint2*)(feat16 + (size_t)i * 2) = make_uint2(lo, hi);
    }
}

// ---------------- W -> transposed bf16: Wt[s][c(256)][k(128)] ----------------
__global__ __launch_bounds__(256) void cvt_w_kernel(
    const float* __restrict__ W, unsigned short* __restrict__ Wt, int total)
{
    int tid = blockIdx.x * 256 + threadIdx.x;
    if (tid >= total) return;
    int i = tid & 127;
    int c = (tid >> 7) & 255;
    int s = tid >> 15;
    float v = W[(size_t)s * 32768 + (size_t)(((c >> 7) << 7) + i) * 128 + (c & 127)];
    Wt[tid] = (unsigned short)f2bf(v);
}

// ---------------- proj via MFMA, Wk in LDS (swizzled) ----------------------
// a8[node][p]  (fp8): feature j=(p&7)*16+(p>>3)  stored at p = lrow*8 + jt
// bp16[node][p](bf16): feature j=(p&7)*16+(p>>3) stored at p = lrow*8 + (jt-8)
__global__ __launch_bounds__(256) void proj_mfma_kernel(
    const unsigned short* __restrict__ feat16s,
    const unsigned short* __restrict__ WtAll,
    const float* __restrict__ bvec,
    unsigned char* __restrict__ a8, unsigned short* __restrict__ bp16s,
    int N, int k0)
{
    __shared__ uint4 wlds4[4096];   // 64 KB: Wk staged, 16B-unit XOR swizzle
    const int t = threadIdx.x;
    const int w = t >> 6, l = t & 63;
    const int by = blockIdx.y, k = k0 + by;
    const int row0 = blockIdx.x * 64 + w * 16;
    const unsigned short* Wk = WtAll + (size_t)k * 256 * 128;

    {
        const uint4* Wg = (const uint4*)Wk;
        char* wb = (char*)wlds4;
        for (int i = t; i < 4096; i += 256) {
            int c = i >> 4;
            int swz = (i * 16) ^ ((c & 7) << 4);
            *(uint4*)(wb + swz) = Wg[i];
        }
    }
    __syncthreads();

    const int lrow = l & 15;
    const int rs = l >> 4;
    const int lk = rs * 8;

    f32x4 acc[16];
    #pragma unroll
    for (int jt = 0; jt < 16; ++jt) acc[jt] = (f32x4){0.f, 0.f, 0.f, 0.f};

    const int arow = row0 + lrow;
    const bool aok = arow < N;
    const unsigned short* ap = feat16s + (size_t)arow * 128 + lk;
    const char* wb = (const char*)wlds4;

    #pragma unroll
    for (int kk = 0; kk < 4; ++kk) {
        short8v af = {0, 0, 0, 0, 0, 0, 0, 0};
        if (aok) af = *(const short8v*)(ap + kk * 32);
        #pragma unroll
        for (int jt = 0; jt < 16; ++jt) {
            int c = jt * 16 + lrow;
            int byte = (c * 256 + kk * 64 + rs * 16) ^ ((c & 7) << 4);
            short8v bf = *(const short8v*)(wb + byte);
            acc[jt] = __builtin_amdgcn_mfma_f32_16x16x32_bf16(af, bf, acc[jt], 0, 0, 0);
        }
    }

    unsigned char*  a8k   = a8    + (size_t)by * N * 128;
    unsigned short* bp16k = bp16s + (size_t)by * N * 128;

    float bias[8];
    #pragma unroll
    for (int i = 0; i < 8; ++i) bias[i] = bvec[(size_t)k * F + i * 16 + lrow];

    #pragma unroll
    for (int r = 0; r < 4; ++r) {
        int node = row0 + rs * 4 + r;
        if (node >= N) continue;
        int w0i = __builtin_amdgcn_cvt_pk_fp8_f32(acc[0][r], acc[1][r], 0, false);
        w0i = __builtin_amdgcn_cvt_pk_fp8_f32(acc[2][r], acc[3][r], w0i, true);
        int w1i = __builtin_amdgcn_cvt_pk_fp8_f32(acc[4][r], acc[5][r], 0, false);
        w1i = __builtin_amdgcn_cvt_pk_fp8_f32(acc[6][r], acc[7][r], w1i, true);
        *(uint2*)(a8k + (size_t)node * 128 + lrow * 8) =
            make_uint2((unsigned)w0i, (unsigned)w1i);
        uint4 o;
        o.x = f2bf(acc[8][r]  + bias[0]) | (f2bf(acc[9][r]  + bias[1]) << 16);
        o.y = f2bf(acc[10][r] + bias[2]) | (f2bf(acc[11][r] + bias[3]) << 16);
        o.z = f2bf(acc[12][r] + bias[4]) | (f2bf(acc[13][r] + bias[5]) << 16);
        o.w = f2bf(acc[14][r] + bias[6]) | (f2bf(acc[15][r] + bias[7]) << 16);
        *(uint4*)(bp16k + (size_t)node * 128 + lrow * 8) = o;
    }
}

// ============= bucket-binned CSR build (N <= 65536 path) =============
__global__ __launch_bounds__(256) void bucket_count_kernel(
    const int* __restrict__ dst, int* __restrict__ bkt_cnt,
    int E, int SE, int NB, int NBS)
{
    __shared__ int hist[1024];
    const int t = threadIdx.x;
    for (int i = t; i < NBS; i += 256) hist[i] = 0;
    __syncthreads();
    const int chunk = (SE + gridDim.x - 1) / gridDim.x;
    const int e0 = blockIdx.x * chunk;
    const int e1 = min(SE, e0 + chunk);
    for (int e = e0 + t; e < e1; e += 256) {
        int s = e / E;
        atomicAdd(&hist[s * NB + (dst[e] >> 8)], 1);
    }
    __syncthreads();
    for (int i = t; i < NBS; i += 256)
        if (hist[i]) atomicAdd(&bkt_cnt[i], hist[i]);
}

__global__ __launch_bounds__(1024) void bucket_scan_kernel(
    const int* __restrict__ bkt_cnt, int* __restrict__ bkt_off,
    int* __restrict__ bkt_cur, int NBS)
{
    __shared__ int buf[1024];
    const int t = threadIdx.x;
    buf[t] = (t < NBS) ? bkt_cnt[t] : 0;
    __syncthreads();
    for (int off = 1; off < 1024; off <<= 1) {
        int x = (t >= off) ? buf[t - off] : 0;
        __syncthreads();
        buf[t] += x;
        __syncthreads();
    }
    if (t <= NBS) {
        int v = (t == 0) ? 0 : buf[t - 1];
        bkt_off[t] = v;
        if (t < NBS) bkt_cur[t] = v;
    }
}

__global__ __launch_bounds__(256) void bucket_scatter_kernel(
    const int* __restrict__ src, const int* __restrict__ dst,
    int* __restrict__ bkt_cur, unsigned* __restrict__ recs,
    int E, int SE, int NB, int NBS)
{
    __shared__ int hist[1024];
    __shared__ int base[1024];
    const int t = threadIdx.x;
    for (int i = t; i < NBS; i += 256) hist[i] = 0;
    __syncthreads();
    const int chunk = (SE + gridDim.x - 1) / gridDim.x;
    const int e0 = blockIdx.x * chunk;
    const int e1 = min(SE, e0 + chunk);
    for (int e = e0 + t; e < e1; e += 256) {
        int s = e / E;
        atomicAdd(&hist[s * NB + (dst[e] >> 8)], 1);
    }
    __syncthreads();
    for (int i = t; i < NBS; i += 256) {
        int h = hist[i];
        if (h) base[i] = atomicAdd(&bkt_cur[i], h);
        hist[i] = 0;
    }
    __syncthreads();
    for (int e = e0 + t; e < e1; e += 256) {
        int s = e / E;
        int d = dst[e];
        int gb = s * NB + (d >> 8);
        int lo = atomicAdd(&hist[gb], 1);
        recs[base[gb] + lo] = (unsigned)src[e] | ((unsigned)(d & 255) << 16);
    }
}

__global__ __launch_bounds__(256) void node_count_bucket_kernel(
    const unsigned* __restrict__ recs, const int* __restrict__ bkt_off,
    int* __restrict__ cnt, int N, int NB)
{
    __shared__ int hist[256];
    const int t = threadIdx.x;
    const int gb = blockIdx.x;
    const int s = gb / NB;
    const int node0 = (gb % NB) << 8;
    hist[t] = 0;
    __syncthreads();
    const int r0 = bkt_off[gb], r1 = bkt_off[gb + 1];
    for (int r = r0 + t; r < r1; r += 256)
        atomicAdd(&hist[(recs[r] >> 16) & 255], 1);
    __syncthreads();
    int node = node0 + t;
    if (node < N) cnt[(size_t)s * N + node] = hist[t];
}

__global__ __launch_bounds__(256) void partial_kernel(
    const int* __restrict__ cnt, int* __restrict__ partials, int N, int BPS)
{
    __shared__ int red[256];
    const int s = blockIdx.y, b = blockIdx.x, t = threadIdx.x;
    int i = b * 256 + t;
    red[t] = (i < N) ? cnt[(size_t)s * N + i] : 0;
    __syncthreads();
    #pragma unroll
    for (int off = 128; off; off >>= 1) {
        if (t < off) red[t] += red[t + off];
        __syncthreads();
    }
    if (t == 0) partials[s * BPS + b] = red[0];
}

__global__ __launch_bounds__(1024) void scan_partials_kernel(
    const int* __restrict__ partials, int* __restrict__ scanned,
    int* __restrict__ row_off, int S, int BPS, int N)
{
    __shared__ int buf[1024];
    const int t = threadIdx.x;
    const int total = S * BPS;
    buf[t] = (t < total) ? partials[t] : 0;
    __syncthreads();
    for (int off = 1; off < 1024; off <<= 1) {
        int x = (t >= off) ? buf[t - off] : 0;
        __syncthreads();
        buf[t] += x;
        __syncthreads();
    }
    if (t < total) {
        int s = t / BPS;
        int g_excl = (t == 0) ? 0 : buf[t - 1];
        int base = (s == 0) ? 0 : buf[s * BPS - 1];
        scanned[t] = g_excl - base;
    }
    if (t < S) {
        int end  = buf[(t + 1) * BPS - 1];
        int base = (t == 0) ? 0 : buf[t * BPS - 1];
        row_off[(size_t)t * (N + 1) + N] = end - base;
    }
}

__global__ __launch_bounds__(256) void emit_kernel(
    const int* __restrict__ cnt, const int* __restrict__ scanned,
    int* __restrict__ row_off, int N, int BPS)
{
    __shared__ int buf[256];
    const int s = blockIdx.y, b = blockIdx.x, t = threadIdx.x;
    int i = b * 256 + t;
    int v = (i < N) ? cnt[(size_t)s * N + i] : 0;
    buf[t] = v;
    __syncthreads();
    for (int off = 1; off < 256; off <<= 1) {
        int x = (t >= off) ? buf[t - off] : 0;
        __syncthreads();
        buf[t] += x;
        __syncthreads();
    }
    if (i < N)
        row_off[(size_t)s * (N + 1) + i] = scanned[s * BPS + b] + buf[t] - v;
}

__global__ __launch_bounds__(256) void csr_fill_bucket_kernel(
    const unsigned* __restrict__ recs, const int* __restrict__ bkt_off,
    const int* __restrict__ row_off, int* __restrict__ src_csr,
    int N, int E, int NB)
{
    __shared__ int cur[256];
    const int t = threadIdx.x;
    const int gb = blockIdx.x;
    const int s = gb / NB;
    const int node0 = (gb % NB) << 8;
    int node = node0 + t;
    cur[t] = (node < N) ? row_off[(size_t)s * (N + 1) + node] : 0;
    __syncthreads();
    int* csr = src_csr + (size_t)s * E;
    const int r0 = bkt_off[gb], r1 = bkt_off[gb + 1];
    for (int r = r0 + t; r < r1; r += 256) {
        unsigned rec = recs[r];
        int pos = atomicAdd(&cur[(rec >> 16) & 255], 1);
        csr[pos] = (int)(rec & 0xFFFFu);
    }
}

// ============= fallback CSR build (N > 65536) =============
__global__ __launch_bounds__(256) void count_all_kernel(
    const int* __restrict__ dst, int* __restrict__ cnt, int E, int SE, int N)
{
    int e = blockIdx.x * 256 + threadIdx.x;
    if (e < SE) {
        int s = e / E;
        atomicAdd(&cnt[(size_t)s * N + dst[e]], 1);
    }
}
__global__ __launch_bounds__(256) void emit_cursor_kernel(
    const int* __restrict__ row_off, int* __restrict__ cursor, int N)
{
    const int s = blockIdx.y;
    int i = blockIdx.x * 256 + threadIdx.x;
    if (i < N) cursor[(size_t)s * N + i] = row_off[(size_t)s * (N + 1) + i];
}
__global__ __launch_bounds__(256) void fill_all_kernel(
    const int* __restrict__ src, const int* __restrict__ dst,
    int* __restrict__ cursor, int* __restrict__ src_csr,
    int E, int SE, int N)
{
    int e = blockIdx.x * 256 + threadIdx.x;
    if (e < SE) {
        int s = e / E;
        int pos = atomicAdd(&cursor[(size_t)s * N + dst[e]], 1);
        src_csr[(size_t)s * E + pos] = src[e];
    }
}

// ------------- fused single-pass attention+softmax+gather (persistent) -----
// Grid-stride: each wave strides over nodes of ONE space (s = bid % B).
// 16 lanes/edge, 4 edges per iter; per-space constants hoisted; no prefetch.
__global__ __launch_bounds__(256) void fused_kernel(
    const uint4* __restrict__ feat16, const uint2* __restrict__ a8,
    const uint4* __restrict__ bp16, const float* __restrict__ wout,
    const int* __restrict__ src_csr_all, const int* __restrict__ row_off_all,
    float* __restrict__ out, int N, int S, int E, int k0, int B)
{
    const int wslot = threadIdx.x >> 6;
    const int lane = threadIdx.x & 63;
    const int eg = lane >> 4;
    const int fl = lane & 15;

    const int by = blockIdx.x % B;           // space slot (XCD affinity)
    const int k = k0 + by;
    const int widx = (blockIdx.x / B) * 4 + wslot;
    const int wstride = (gridDim.x / B) * 4;

    const int* row_off = row_off_all + (size_t)k * (N + 1);
    const int* src_csr = src_csr_all + (size_t)k * E;
    const uint2* a8k   = a8   + (size_t)by * N * 16;
    const uint4* bp16k = bp16 + (size_t)by * N * 16;

    const float C2  = 2.8853900817779268f;   // 2*log2(e)
    const float L2E = 1.4426950408889634f;

    // per-space constants (hoisted out of node loop)
    const float* wk = wout + (size_t)k * F;
    float wv[8];
    #pragma unroll
    for (int i = 0; i < 8; ++i) wv[i] = wk[i * 16 + fl];
    float sumw = 0.f, sabs = 0.f;
    #pragma unroll
    for (int i = 0; i < 8; ++i) { sumw += wv[i]; sabs += fabsf(wv[i]); }
    #pragma unroll
    for (int off = 1; off < 16; off <<= 1) {
        sumw += __shfl_xor(sumw, off);
        sabs += __shfl_xor(sabs, off);
    }
    const float negswl = -sabs * L2E;   // softmax shift (log2 domain)

    for (int node = widx; node < N; node += wstride) {
        const int beg = row_off[node];
        const int cnt = row_off[node + 1] - beg;
        float* outp = out + (size_t)node * (S * F) + k * F;
        if (cnt == 0) {
            if (eg == 0) {
                *(float4*)(outp + fl * 8)     = make_float4(0.f, 0.f, 0.f, 0.f);
                *(float4*)(outp + fl * 8 + 4) = make_float4(0.f, 0.f, 0.f, 0.f);
            }
            continue;
        }

        uint4 bv = bp16k[(size_t)node * 16 + fl];
        float bc[8];
        bc[0] = bf_lo(bv.x) * C2; bc[1] = bf_hi(bv.x) * C2;
        bc[2] = bf_lo(bv.y) * C2; bc[3] = bf_hi(bv.y) * C2;
        bc[4] = bf_lo(bv.z) * C2; bc[5] = bf_hi(bv.z) * C2;
        bc[6] = bf_lo(bv.w) * C2; bc[7] = bf_hi(bv.w) * C2;

        float ssum = 0.f;
        float acc[8] = {0.f, 0.f, 0.f, 0.f, 0.f, 0.f, 0.f, 0.f};
        for (int chunk = 0; chunk < cnt; chunk += 64) {
            int idx = chunk + lane;
            int sv = (idx < cnt) ? src_csr[beg + idx] : 0;
            int cend = min(64, cnt - chunk);
            for (int q = 0; q < cend; q += 4) {
                int my = q + eg;
                int sj = __shfl(sv, my);
                uint2 av8 = a8k[(size_t)sj * 16 + fl];
                uint4 fv  = feat16[(size_t)sj * 16 + fl];
                f32x2 a01 = __builtin_amdgcn_cvt_pk_f32_fp8(av8.x, false);
                f32x2 a23 = __builtin_amdgcn_cvt_pk_f32_fp8(av8.x, true);
                f32x2 a45 = __builtin_amdgcn_cvt_pk_f32_fp8(av8.y, false);
                f32x2 a67 = __builtin_amdgcn_cvt_pk_f32_fp8(av8.y, true);
                float pr;
                pr  = wv[0] * __builtin_amdgcn_rcpf(__builtin_exp2f(fmaf(a01.x, C2, bc[0])) + 1.f);
                pr += wv[1] * __builtin_amdgcn_rcpf(__builtin_exp2f(fmaf(a01.y, C2, bc[1])) + 1.f);
                pr += wv[2] * __builtin_amdgcn_rcpf(__builtin_exp2f(fmaf(a23.x, C2, bc[2])) + 1.f);
                pr += wv[3] * __builtin_amdgcn_rcpf(__builtin_exp2f(fmaf(a23.y, C2, bc[3])) + 1.f);
                pr += wv[4] * __builtin_amdgcn_rcpf(__builtin_exp2f(fmaf(a45.x, C2, bc[4])) + 1.f);
                pr += wv[5] * __builtin_amdgcn_rcpf(__builtin_exp2f(fmaf(a45.y, C2, bc[5])) + 1.f);
                pr += wv[6] * __builtin_amdgcn_rcpf(__builtin_exp2f(fmaf(a67.x, C2, bc[6])) + 1.f);
                pr += wv[7] * __builtin_amdgcn_rcpf(__builtin_exp2f(fmaf(a67.y, C2, bc[7])) + 1.f);
                pr += __shfl_xor(pr, 1);
                pr += __shfl_xor(pr, 2);
                pr += __shfl_xor(pr, 4);
                pr += __shfl_xor(pr, 8);
                float p = sumw - 2.f * pr;                    // edge score e
                float ex = (my < cend) ? __builtin_exp2f(fmaf(p, L2E, negswl)) : 0.f;
                ssum += ex;
                acc[0] = fmaf(ex, bf_lo(fv.x), acc[0]);
                acc[1] = fmaf(ex, bf_hi(fv.x), acc[1]);
                acc[2] = fmaf(ex, bf_lo(fv.y), acc[2]);
                acc[3] = fmaf(ex, bf_hi(fv.y), acc[3]);
                acc[4] = fmaf(ex, bf_lo(fv.z), acc[4]);
                acc[5] = fmaf(ex, bf_hi(fv.z), acc[5]);
                acc[6] = fmaf(ex, bf_lo(fv.w), acc[6]);
                acc[7] = fmaf(ex, bf_hi(fv.w), acc[7]);
            }
        }
        ssum += __shfl_xor(ssum, 16);
        ssum += __shfl_xor(ssum, 32);
        #pragma unroll
        for (int j = 0; j < 8; ++j) {
            acc[j] += __shfl_xor(acc[j], 16);
            acc[j] += __shfl_xor(acc[j], 32);
        }
        float inv = __builtin_amdgcn_rcpf(ssum);
        if (eg == 0) {
            *(float4*)(outp + fl * 8) =
                make_float4(acc[0] * inv, acc[1] * inv, acc[2] * inv, acc[3] * inv);
            *(float4*)(outp + fl * 8 + 4) =
                make_float4(acc[4] * inv, acc[5] * inv, acc[6] * inv, acc[7] * inv);
        }
    }
}

extern "C" void kernel_launch(void* const* d_in, const int* in_sizes, int n_in,
                              void* d_out, int out_size, void* d_ws, size_t ws_size,
                              hipStream_t stream) {
    const float* feat = (const float*)d_in[0];
    const int*   src  = (const int*)d_in[1];
    const int*   dst  = (const int*)d_in[2];
    const float* W    = (const float*)d_in[3];
    const float* bvec = (const float*)d_in[4];
    const float* wout = (const float*)d_in[5];
    float* out = (float*)d_out;

    const int N = in_sizes[0] / F;
    const int S = in_sizes[3] / (2 * F * F);
    const int E = in_sizes[1] / S;
    const int SE = S * E;
    const int BPS = (N + 255) / 256;
    const int NB  = (N + 255) >> 8;
    const int NBS = NB * S;
    const bool packed = (N <= 65536) && (NBS <= 1024) && (S * BPS <= 1024);

    size_t fixed = (size_t)N * 256                // feat16
                 + (size_t)S * 32768 * 2          // Wt
                 + (size_t)SE * 4                 // src_csr
                 + (size_t)SE * 4                 // recs
                 + (size_t)S * N * 4              // cnt
                 + (size_t)S * (N + 1) * 4        // row_off
                 + (size_t)S * BPS * 4 * 2        // partials + scanned
                 + (size_t)(NBS + 1) * 4 * 3;     // bkt_cnt/off/cur
    size_t perB = (size_t)N * 128                 // a8
                + (size_t)N * 256;                // bp16
    const int B = (ws_size >= fixed + perB * (size_t)S + 1024) ? S : 1;

    char* p = (char*)d_ws;
    unsigned* feat16     = (unsigned*)p;        p += (size_t)N * 256;
    unsigned char* a8    = (unsigned char*)p;   p += (size_t)B * N * 128;
    unsigned short* bp16 = (unsigned short*)p;  p += (size_t)B * N * 256;
    unsigned short* Wt   = (unsigned short*)p;  p += (size_t)S * 32768 * 2;
    int*      src_csr  = (int*)p;               p += (size_t)SE * 4;
    unsigned* recs     = (unsigned*)p;          p += (size_t)SE * 4;
    int*      cnt      = (int*)p;               p += (size_t)S * N * 4;
    int*      row_off  = (int*)p;               p += (size_t)S * (N + 1) * 4;
    int*      partials = (int*)p;               p += (size_t)S * BPS * 4;
    int*      scanned  = (int*)p;               p += (size_t)S * BPS * 4;
    int*      bkt_cnt  = (int*)p;               p += (size_t)(NBS + 1) * 4;
    int*      bkt_off  = (int*)p;               p += (size_t)(NBS + 1) * 4;
    int*      bkt_cur  = (int*)p;

    const int n4 = N * F / 4;
    const int proj_blocks = (N + 63) / 64;
    const int se_blocks   = (SE + 255) / 256;
    const int wt_total    = S * 256 * 128;

    cvt_feat_kernel<<<2048, 256, 0, stream>>>(feat, feat16, n4);
    cvt_w_kernel<<<(wt_total + 255) / 256, 256, 0, stream>>>(W, Wt, wt_total);

    if (packed) {
        hipMemsetAsync(bkt_cnt, 0, (size_t)NBS * sizeof(int), stream);
        bucket_count_kernel<<<512, 256, 0, stream>>>(dst, bkt_cnt, E, SE, NB, NBS);
        bucket_scan_kernel<<<1, 1024, 0, stream>>>(bkt_cnt, bkt_off, bkt_cur, NBS);
        bucket_scatter_kernel<<<512, 256, 0, stream>>>(src, dst, bkt_cur, recs,
                                                       E, SE, NB, NBS);
        node_count_bucket_kernel<<<NBS, 256, 0, stream>>>(recs, bkt_off, cnt, N, NB);
        partial_kernel<<<dim3(BPS, S), 256, 0, stream>>>(cnt, partials, N, BPS);
        scan_partials_kernel<<<1, 1024, 0, stream>>>(partials, scanned, row_off,
                                                     S, BPS, N);
        emit_kernel<<<dim3(BPS, S), 256, 0, stream>>>(cnt, scanned, row_off, N, BPS);
        csr_fill_bucket_kernel<<<NBS, 256, 0, stream>>>(recs, bkt_off, row_off,
                                                        src_csr, N, E, NB);
    } else {
        hipMemsetAsync(cnt, 0, (size_t)S * N * sizeof(int), stream);
        count_all_kernel<<<se_blocks, 256, 0, stream>>>(dst, cnt, E, SE, N);
        partial_kernel<<<dim3(BPS, S), 256, 0, stream>>>(cnt, partials, N, BPS);
        scan_partials_kernel<<<1, 1024, 0, stream>>>(partials, scanned, row_off,
                                                     S, BPS, N);
        emit_kernel<<<dim3(BPS, S), 256, 0, stream>>>(cnt, scanned, row_off, N, BPS);
        emit_cursor_kernel<<<dim3(BPS, S), 256, 0, stream>>>(row_off, cnt, N);
        fill_all_kernel<<<se_blocks, 256, 0, stream>>>(src, dst, cnt, src_csr,
                                                       E, SE, N);
    }

    for (int k0 = 0; k0 < S; k0 += B) {
        proj_mfma_kernel<<<dim3(proj_blocks, B), 256, 0, stream>>>(
            (const unsigned short*)feat16, Wt, bvec, a8, bp16, N, k0);
        fused_kernel<<<2048, 256, 0, stream>>>(
            (const uint4*)feat16, (const uint2*)a8, (const uint4*)bp16, wout,
            src_csr, row_off, out, N, S, E, k0, B);
    }
}

// Round 12
// 362.404 us; speedup vs baseline: 1.1641x; 1.1641x over previous
//
#include <hip/hip_runtime.h>
#include <hip/hip_bf16.h>

// AngleOrientedConv: per space k (S=4):
//   a  = feat @ W[k][:128,:];  bp = feat @ W[k][128:,:] + b[k]
//   e  = sum_j tanh(a[src][j] + bp[dst][j]) * w[k][j]
//   segment softmax over dst; out[:, k*128:(k+1)*128] = sum alpha * feat[src]
//
// Round 12: restore round-8 exactly (best measured: 368us). Post-r8 probes all
// regressed: prefetch (r7,r10: -5..7%), LDS-bucket fusion (r9: -19%),
// persistent grid (r11: -22%). The fused kernel is bound by the fabric/L3
// random-gather service rate (~2.6TB/s aggregate) at 78% occupancy with a
// working set ~10x the per-XCD L2; every other axis (VALU, bytes, latency
// overlap, wave shape) has been A/B'd and is not the limit.

#define F 128

typedef __attribute__((ext_vector_type(8))) short short8v;   // 8 bf16
typedef __attribute__((ext_vector_type(4))) float f32x4;
typedef __attribute__((ext_vector_type(2))) float f32x2;

__device__ __forceinline__ unsigned f2bf(float x) {  // round-to-nearest-even
    unsigned u = __float_as_uint(x);
    unsigned r = ((u >> 16) & 1u) + 0x7fffu;
    return (u + r) >> 16;
}
__device__ __forceinline__ float bf_lo(unsigned v) { return __uint_as_float(v << 16); }
__device__ __forceinline__ float bf_hi(unsigned v) { return __uint_as_float(v & 0xffff0000u); }

// ---------------- feat -> bf16 (once) ----------------
__global__ __launch_bounds__(256) void cvt_feat_kernel(
    const float* __restrict__ feat, unsigned* __restrict__ feat16, int n4)
{
    for (int i = blockIdx.x * 256 + threadIdx.x; i < n4; i += gridDim.x * 256) {
        float4 v = *(const float4*)(feat + (size_t)i * 4);
        unsigned lo = f2bf(v.x) | (f2bf(v.y) << 16);
        unsigned hi = f2bf(v.z) | (f2bf(v.w) << 16);
        *(uint2*)(feat16 + (size_t)i * 2) = make_uint2(lo, hi);
    }
}

// ---------------- W -> transposed bf16: Wt[s][c(256)][k(128)] ----------------
__global__ __launch_bounds__(256) void cvt_w_kernel(
    const float* __restrict__ W, unsigned short* __restrict__ Wt, int total)
{
    int tid = blockIdx.x * 256 + threadIdx.x;
    if (tid >= total) return;
    int i = tid & 127;
    int c = (tid >> 7) & 255;
    int s = tid >> 15;
    float v = W[(size_t)s * 32768 + (size_t)(((c >> 7) << 7) + i) * 128 + (c & 127)];
    Wt[tid] = (unsigned short)f2bf(v);
}

// ---------------- proj via MFMA, Wk in LDS (swizzled) ----------------------
// a8[node][p]  (fp8): feature j=(p&7)*16+(p>>3)  stored at p = lrow*8 + jt
// bp16[node][p](bf16): feature j=(p&7)*16+(p>>3) stored at p = lrow*8 + (jt-8)
__global__ __launch_bounds__(256) void proj_mfma_kernel(
    const unsigned short* __restrict__ feat16s,
    const unsigned short* __restrict__ WtAll,
    const float* __restrict__ bvec,
    unsigned char* __restrict__ a8, unsigned short* __restrict__ bp16s,
    int N, int k0)
{
    __shared__ uint4 wlds4[4096];   // 64 KB: Wk staged, 16B-unit XOR swizzle
    const int t = threadIdx.x;
    const int w = t >> 6, l = t & 63;
    const int by = blockIdx.y, k = k0 + by;
    const int row0 = blockIdx.x * 64 + w * 16;
    const unsigned short* Wk = WtAll + (size_t)k * 256 * 128;

    {
        const uint4* Wg = (const uint4*)Wk;
        char* wb = (char*)wlds4;
        for (int i = t; i < 4096; i += 256) {
            int c = i >> 4;
            int swz = (i * 16) ^ ((c & 7) << 4);
            *(uint4*)(wb + swz) = Wg[i];
        }
    }
    __syncthreads();

    const int lrow = l & 15;
    const int rs = l >> 4;
    const int lk = rs * 8;

    f32x4 acc[16];
    #pragma unroll
    for (int jt = 0; jt < 16; ++jt) acc[jt] = (f32x4){0.f, 0.f, 0.f, 0.f};

    const int arow = row0 + lrow;
    const bool aok = arow < N;
    const unsigned short* ap = feat16s + (size_t)arow * 128 + lk;
    const char* wb = (const char*)wlds4;

    #pragma unroll
    for (int kk = 0; kk < 4; ++kk) {
        short8v af = {0, 0, 0, 0, 0, 0, 0, 0};
        if (aok) af = *(const short8v*)(ap + kk * 32);
        #pragma unroll
        for (int jt = 0; jt < 16; ++jt) {
            int c = jt * 16 + lrow;
            int byte = (c * 256 + kk * 64 + rs * 16) ^ ((c & 7) << 4);
            short8v bf = *(const short8v*)(wb + byte);
            acc[jt] = __builtin_amdgcn_mfma_f32_16x16x32_bf16(af, bf, acc[jt], 0, 0, 0);
        }
    }

    unsigned char*  a8k   = a8    + (size_t)by * N * 128;
    unsigned short* bp16k = bp16s + (size_t)by * N * 128;

    float bias[8];
    #pragma unroll
    for (int i = 0; i < 8; ++i) bias[i] = bvec[(size_t)k * F + i * 16 + lrow];

    #pragma unroll
    for (int r = 0; r < 4; ++r) {
        int node = row0 + rs * 4 + r;
        if (node >= N) continue;
        // a-side: 8 fp8 bytes at p = lrow*8 .. +7  (p&7 = jt)
        int w0i = __builtin_amdgcn_cvt_pk_fp8_f32(acc[0][r], acc[1][r], 0, false);
        w0i = __builtin_amdgcn_cvt_pk_fp8_f32(acc[2][r], acc[3][r], w0i, true);
        int w1i = __builtin_amdgcn_cvt_pk_fp8_f32(acc[4][r], acc[5][r], 0, false);
        w1i = __builtin_amdgcn_cvt_pk_fp8_f32(acc[6][r], acc[7][r], w1i, true);
        *(uint2*)(a8k + (size_t)node * 128 + lrow * 8) =
            make_uint2((unsigned)w0i, (unsigned)w1i);
        // bp-side: 8 bf16 at p = lrow*8 .. +7  (p&7 = jt-8), + bias
        uint4 o;
        o.x = f2bf(acc[8][r]  + bias[0]) | (f2bf(acc[9][r]  + bias[1]) << 16);
        o.y = f2bf(acc[10][r] + bias[2]) | (f2bf(acc[11][r] + bias[3]) << 16);
        o.z = f2bf(acc[12][r] + bias[4]) | (f2bf(acc[13][r] + bias[5]) << 16);
        o.w = f2bf(acc[14][r] + bias[6]) | (f2bf(acc[15][r] + bias[7]) << 16);
        *(uint4*)(bp16k + (size_t)node * 128 + lrow * 8) = o;
    }
}

// ============= bucket-binned CSR build (N <= 65536 path) =============
__global__ __launch_bounds__(256) void bucket_count_kernel(
    const int* __restrict__ dst, int* __restrict__ bkt_cnt,
    int E, int SE, int NB, int NBS)
{
    __shared__ int hist[1024];
    const int t = threadIdx.x;
    for (int i = t; i < NBS; i += 256) hist[i] = 0;
    __syncthreads();
    const int chunk = (SE + gridDim.x - 1) / gridDim.x;
    const int e0 = blockIdx.x * chunk;
    const int e1 = min(SE, e0 + chunk);
    for (int e = e0 + t; e < e1; e += 256) {
        int s = e / E;
        atomicAdd(&hist[s * NB + (dst[e] >> 8)], 1);
    }
    __syncthreads();
    for (int i = t; i < NBS; i += 256)
        if (hist[i]) atomicAdd(&bkt_cnt[i], hist[i]);
}

__global__ __launch_bounds__(1024) void bucket_scan_kernel(
    const int* __restrict__ bkt_cnt, int* __restrict__ bkt_off,
    int* __restrict__ bkt_cur, int NBS)
{
    __shared__ int buf[1024];
    const int t = threadIdx.x;
    buf[t] = (t < NBS) ? bkt_cnt[t] : 0;
    __syncthreads();
    for (int off = 1; off < 1024; off <<= 1) {
        int x = (t >= off) ? buf[t - off] : 0;
        __syncthreads();
        buf[t] += x;
        __syncthreads();
    }
    if (t <= NBS) {
        int v = (t == 0) ? 0 : buf[t - 1];
        bkt_off[t] = v;
        if (t < NBS) bkt_cur[t] = v;
    }
}

__global__ __launch_bounds__(256) void bucket_scatter_kernel(
    const int* __restrict__ src, const int* __restrict__ dst,
    int* __restrict__ bkt_cur, unsigned* __restrict__ recs,
    int E, int SE, int NB, int NBS)
{
    __shared__ int hist[1024];
    __shared__ int base[1024];
    const int t = threadIdx.x;
    for (int i = t; i < NBS; i += 256) hist[i] = 0;
    __syncthreads();
    const int chunk = (SE + gridDim.x - 1) / gridDim.x;
    const int e0 = blockIdx.x * chunk;
    const int e1 = min(SE, e0 + chunk);
    for (int e = e0 + t; e < e1; e += 256) {
        int s = e / E;
        atomicAdd(&hist[s * NB + (dst[e] >> 8)], 1);
    }
    __syncthreads();
    for (int i = t; i < NBS; i += 256) {
        int h = hist[i];
        if (h) base[i] = atomicAdd(&bkt_cur[i], h);
        hist[i] = 0;
    }
    __syncthreads();
    for (int e = e0 + t; e < e1; e += 256) {
        int s = e / E;
        int d = dst[e];
        int gb = s * NB + (d >> 8);
        int lo = atomicAdd(&hist[gb], 1);
        recs[base[gb] + lo] = (unsigned)src[e] | ((unsigned)(d & 255) << 16);
    }
}

__global__ __launch_bounds__(256) void node_count_bucket_kernel(
    const unsigned* __restrict__ recs, const int* __restrict__ bkt_off,
    int* __restrict__ cnt, int N, int NB)
{
    __shared__ int hist[256];
    const int t = threadIdx.x;
    const int gb = blockIdx.x;
    const int s = gb / NB;
    const int node0 = (gb % NB) << 8;
    hist[t] = 0;
    __syncthreads();
    const int r0 = bkt_off[gb], r1 = bkt_off[gb + 1];
    for (int r = r0 + t; r < r1; r += 256)
        atomicAdd(&hist[(recs[r] >> 16) & 255], 1);
    __syncthreads();
    int node = node0 + t;
    if (node < N) cnt[(size_t)s * N + node] = hist[t];
}

__global__ __launch_bounds__(256) void partial_kernel(
    const int* __restrict__ cnt, int* __restrict__ partials, int N, int BPS)
{
    __shared__ int red[256];
    const int s = blockIdx.y, b = blockIdx.x, t = threadIdx.x;
    int i = b * 256 + t;
    red[t] = (i < N) ? cnt[(size_t)s * N + i] : 0;
    __syncthreads();
    #pragma unroll
    for (int off = 128; off; off >>= 1) {
        if (t < off) red[t] += red[t + off];
        __syncthreads();
    }
    if (t == 0) partials[s * BPS + b] = red[0];
}

__global__ __launch_bounds__(1024) void scan_partials_kernel(
    const int* __restrict__ partials, int* __restrict__ scanned,
    int* __restrict__ row_off, int S, int BPS, int N)
{
    __shared__ int buf[1024];
    const int t = threadIdx.x;
    const int total = S * BPS;
    buf[t] = (t < total) ? partials[t] : 0;
    __syncthreads();
    for (int off = 1; off < 1024; off <<= 1) {
        int x = (t >= off) ? buf[t - off] : 0;
        __syncthreads();
        buf[t] += x;
        __syncthreads();
    }
    if (t < total) {
        int s = t / BPS;
        int g_excl = (t == 0) ? 0 : buf[t - 1];
        int base = (s == 0) ? 0 : buf[s * BPS - 1];
        scanned[t] = g_excl - base;
    }
    if (t < S) {
        int end  = buf[(t + 1) * BPS - 1];
        int base = (t == 0) ? 0 : buf[t * BPS - 1];
        row_off[(size_t)t * (N + 1) + N] = end - base;
    }
}

__global__ __launch_bounds__(256) void emit_kernel(
    const int* __restrict__ cnt, const int* __restrict__ scanned,
    int* __restrict__ row_off, int N, int BPS)
{
    __shared__ int buf[256];
    const int s = blockIdx.y, b = blockIdx.x, t = threadIdx.x;
    int i = b * 256 + t;
    int v = (i < N) ? cnt[(size_t)s * N + i] : 0;
    buf[t] = v;
    __syncthreads();
    for (int off = 1; off < 256; off <<= 1) {
        int x = (t >= off) ? buf[t - off] : 0;
        __syncthreads();
        buf[t] += x;
        __syncthreads();
    }
    if (i < N)
        row_off[(size_t)s * (N + 1) + i] = scanned[s * BPS + b] + buf[t] - v;
}

__global__ __launch_bounds__(256) void csr_fill_bucket_kernel(
    const unsigned* __restrict__ recs, const int* __restrict__ bkt_off,
    const int* __restrict__ row_off, int* __restrict__ src_csr,
    int N, int E, int NB)
{
    __shared__ int cur[256];
    const int t = threadIdx.x;
    const int gb = blockIdx.x;
    const int s = gb / NB;
    const int node0 = (gb % NB) << 8;
    int node = node0 + t;
    cur[t] = (node < N) ? row_off[(size_t)s * (N + 1) + node] : 0;
    __syncthreads();
    int* csr = src_csr + (size_t)s * E;
    const int r0 = bkt_off[gb], r1 = bkt_off[gb + 1];
    for (int r = r0 + t; r < r1; r += 256) {
        unsigned rec = recs[r];
        int pos = atomicAdd(&cur[(rec >> 16) & 255], 1);
        csr[pos] = (int)(rec & 0xFFFFu);
    }
}

// ============= fallback CSR build (N > 65536) =============
__global__ __launch_bounds__(256) void count_all_kernel(
    const int* __restrict__ dst, int* __restrict__ cnt, int E, int SE, int N)
{
    int e = blockIdx.x * 256 + threadIdx.x;
    if (e < SE) {
        int s = e / E;
        atomicAdd(&cnt[(size_t)s * N + dst[e]], 1);
    }
}
__global__ __launch_bounds__(256) void emit_cursor_kernel(
    const int* __restrict__ row_off, int* __restrict__ cursor, int N)
{
    const int s = blockIdx.y;
    int i = blockIdx.x * 256 + threadIdx.x;
    if (i < N) cursor[(size_t)s * N + i] = row_off[(size_t)s * (N + 1) + i];
}
__global__ __launch_bounds__(256) void fill_all_kernel(
    const int* __restrict__ src, const int* __restrict__ dst,
    int* __restrict__ cursor, int* __restrict__ src_csr,
    int E, int SE, int N)
{
    int e = blockIdx.x * 256 + threadIdx.x;
    if (e < SE) {
        int s = e / E;
        int pos = atomicAdd(&cursor[(size_t)s * N + dst[e]], 1);
        src_csr[(size_t)s * E + pos] = src[e];
    }
}

// ------------- fused single-pass attention+softmax+gather (fp8 a) ----------
// wave per dst node; 16 lanes/edge, 4 edges per iter. lane fl's 8 features are
// j = i*16+fl (permuted layout). No max pass (|e| <= sum|w|). No prefetch.
__global__ __launch_bounds__(256) void fused_kernel(
    const uint4* __restrict__ feat16, const uint2* __restrict__ a8,
    const uint4* __restrict__ bp16, const float* __restrict__ wout,
    const int* __restrict__ src_csr_all, const int* __restrict__ row_off_all,
    float* __restrict__ out, int N, int S, int E, int k0)
{
    const int by = blockIdx.y, k = k0 + by;
    const int node = blockIdx.x * 4 + (threadIdx.x >> 6);
    const int lane = threadIdx.x & 63;
    const int eg = lane >> 4;
    const int fl = lane & 15;
    if (node >= N) return;

    const int* row_off = row_off_all + (size_t)k * (N + 1);
    const int* src_csr = src_csr_all + (size_t)k * E;
    const uint2* a8k  = a8   + (size_t)by * N * 16;
    const uint4* bp16k = bp16 + (size_t)by * N * 16;

    const int beg = row_off[node];
    const int cnt = row_off[node + 1] - beg;
    float* outp = out + (size_t)node * (S * F) + k * F;
    if (cnt == 0) {
        if (eg == 0) {
            *(float4*)(outp + fl * 8)     = make_float4(0.f, 0.f, 0.f, 0.f);
            *(float4*)(outp + fl * 8 + 4) = make_float4(0.f, 0.f, 0.f, 0.f);
        }
        return;
    }

    const float C2  = 2.8853900817779268f;   // 2*log2(e)
    const float L2E = 1.4426950408889634f;

    uint4 bv = bp16k[(size_t)node * 16 + fl];
    float bc[8];
    bc[0] = bf_lo(bv.x) * C2; bc[1] = bf_hi(bv.x) * C2;
    bc[2] = bf_lo(bv.y) * C2; bc[3] = bf_hi(bv.y) * C2;
    bc[4] = bf_lo(bv.z) * C2; bc[5] = bf_hi(bv.z) * C2;
    bc[6] = bf_lo(bv.w) * C2; bc[7] = bf_hi(bv.w) * C2;
    const float* wk = wout + (size_t)k * F;
    float wv[8];
    #pragma unroll
    for (int i = 0; i < 8; ++i) wv[i] = wk[i * 16 + fl];

    float sumw = 0.f, sabs = 0.f;
    #pragma unroll
    for (int i = 0; i < 8; ++i) { sumw += wv[i]; sabs += fabsf(wv[i]); }
    #pragma unroll
    for (int off = 1; off < 16; off <<= 1) {
        sumw += __shfl_xor(sumw, off);
        sabs += __shfl_xor(sabs, off);
    }
    const float negswl = -sabs * L2E;   // softmax shift (log2 domain)

    float ssum = 0.f;
    float acc[8] = {0.f, 0.f, 0.f, 0.f, 0.f, 0.f, 0.f, 0.f};
    for (int chunk = 0; chunk < cnt; chunk += 64) {
        int idx = chunk + lane;
        int sv = (idx < cnt) ? src_csr[beg + idx] : 0;
        int cend = min(64, cnt - chunk);
        for (int q = 0; q < cend; q += 4) {
            int my = q + eg;
            int sj = __shfl(sv, my);
            uint2 av8 = a8k[(size_t)sj * 16 + fl];
            uint4 fv  = feat16[(size_t)sj * 16 + fl];
            f32x2 a01 = __builtin_amdgcn_cvt_pk_f32_fp8(av8.x, false);
            f32x2 a23 = __builtin_amdgcn_cvt_pk_f32_fp8(av8.x, true);
            f32x2 a45 = __builtin_amdgcn_cvt_pk_f32_fp8(av8.y, false);
            f32x2 a67 = __builtin_amdgcn_cvt_pk_f32_fp8(av8.y, true);
            float pr;
            pr  = wv[0] * __builtin_amdgcn_rcpf(__builtin_exp2f(fmaf(a01.x, C2, bc[0])) + 1.f);
            pr += wv[1] * __builtin_amdgcn_rcpf(__builtin_exp2f(fmaf(a01.y, C2, bc[1])) + 1.f);
            pr += wv[2] * __builtin_amdgcn_rcpf(__builtin_exp2f(fmaf(a23.x, C2, bc[2])) + 1.f);
            pr += wv[3] * __builtin_amdgcn_rcpf(__builtin_exp2f(fmaf(a23.y, C2, bc[3])) + 1.f);
            pr += wv[4] * __builtin_amdgcn_rcpf(__builtin_exp2f(fmaf(a45.x, C2, bc[4])) + 1.f);
            pr += wv[5] * __builtin_amdgcn_rcpf(__builtin_exp2f(fmaf(a45.y, C2, bc[5])) + 1.f);
            pr += wv[6] * __builtin_amdgcn_rcpf(__builtin_exp2f(fmaf(a67.x, C2, bc[6])) + 1.f);
            pr += wv[7] * __builtin_amdgcn_rcpf(__builtin_exp2f(fmaf(a67.y, C2, bc[7])) + 1.f);
            pr += __shfl_xor(pr, 1);
            pr += __shfl_xor(pr, 2);
            pr += __shfl_xor(pr, 4);
            pr += __shfl_xor(pr, 8);
            float p = sumw - 2.f * pr;                    // edge score e
            float ex = (my < cend) ? __builtin_exp2f(fmaf(p, L2E, negswl)) : 0.f;
            ssum += ex;
            acc[0] = fmaf(ex, bf_lo(fv.x), acc[0]);
            acc[1] = fmaf(ex, bf_hi(fv.x), acc[1]);
            acc[2] = fmaf(ex, bf_lo(fv.y), acc[2]);
            acc[3] = fmaf(ex, bf_hi(fv.y), acc[3]);
            acc[4] = fmaf(ex, bf_lo(fv.z), acc[4]);
            acc[5] = fmaf(ex, bf_hi(fv.z), acc[5]);
            acc[6] = fmaf(ex, bf_lo(fv.w), acc[6]);
            acc[7] = fmaf(ex, bf_hi(fv.w), acc[7]);
        }
    }
    ssum += __shfl_xor(ssum, 16);
    ssum += __shfl_xor(ssum, 32);
    #pragma unroll
    for (int j = 0; j < 8; ++j) {
        acc[j] += __shfl_xor(acc[j], 16);
        acc[j] += __shfl_xor(acc[j], 32);
    }
    float inv = __builtin_amdgcn_rcpf(ssum);
    if (eg == 0) {
        *(float4*)(outp + fl * 8) =
            make_float4(acc[0] * inv, acc[1] * inv, acc[2] * inv, acc[3] * inv);
        *(float4*)(outp + fl * 8 + 4) =
            make_float4(acc[4] * inv, acc[5] * inv, acc[6] * inv, acc[7] * inv);
    }
}

extern "C" void kernel_launch(void* const* d_in, const int* in_sizes, int n_in,
                              void* d_out, int out_size, void* d_ws, size_t ws_size,
                              hipStream_t stream) {
    const float* feat = (const float*)d_in[0];
    const int*   src  = (const int*)d_in[1];
    const int*   dst  = (const int*)d_in[2];
    const float* W    = (const float*)d_in[3];
    const float* bvec = (const float*)d_in[4];
    const float* wout = (const float*)d_in[5];
    float* out = (float*)d_out;

    const int N = in_sizes[0] / F;
    const int S = in_sizes[3] / (2 * F * F);
    const int E = in_sizes[1] / S;
    const int SE = S * E;
    const int BPS = (N + 255) / 256;
    const int NB  = (N + 255) >> 8;
    const int NBS = NB * S;
    const bool packed = (N <= 65536) && (NBS <= 1024) && (S * BPS <= 1024);

    size_t fixed = (size_t)N * 256                // feat16
                 + (size_t)S * 32768 * 2          // Wt
                 + (size_t)SE * 4                 // src_csr
                 + (size_t)SE * 4                 // recs
                 + (size_t)S * N * 4              // cnt
                 + (size_t)S * (N + 1) * 4        // row_off
                 + (size_t)S * BPS * 4 * 2        // partials + scanned
                 + (size_t)(NBS + 1) * 4 * 3;     // bkt_cnt/off/cur
    size_t perB = (size_t)N * 128                 // a8
                + (size_t)N * 256;                // bp16
    const int B = (ws_size >= fixed + perB * (size_t)S + 1024) ? S : 1;

    char* p = (char*)d_ws;
    unsigned* feat16     = (unsigned*)p;        p += (size_t)N * 256;
    unsigned char* a8    = (unsigned char*)p;   p += (size_t)B * N * 128;
    unsigned short* bp16 = (unsigned short*)p;  p += (size_t)B * N * 256;
    unsigned short* Wt   = (unsigned short*)p;  p += (size_t)S * 32768 * 2;
    int*      src_csr  = (int*)p;               p += (size_t)SE * 4;
    unsigned* recs     = (unsigned*)p;          p += (size_t)SE * 4;
    int*      cnt      = (int*)p;               p += (size_t)S * N * 4;
    int*      row_off  = (int*)p;               p += (size_t)S * (N + 1) * 4;
    int*      partials = (int*)p;               p += (size_t)S * BPS * 4;
    int*      scanned  = (int*)p;               p += (size_t)S * BPS * 4;
    int*      bkt_cnt  = (int*)p;               p += (size_t)(NBS + 1) * 4;
    int*      bkt_off  = (int*)p;               p += (size_t)(NBS + 1) * 4;
    int*      bkt_cur  = (int*)p;

    const int n4 = N * F / 4;
    const int proj_blocks = (N + 63) / 64;
    const int node_blocks = (N + 3) / 4;
    const int se_blocks   = (SE + 255) / 256;
    const int wt_total    = S * 256 * 128;

    cvt_feat_kernel<<<2048, 256, 0, stream>>>(feat, feat16, n4);
    cvt_w_kernel<<<(wt_total + 255) / 256, 256, 0, stream>>>(W, Wt, wt_total);

    if (packed) {
        hipMemsetAsync(bkt_cnt, 0, (size_t)NBS * sizeof(int), stream);
        bucket_count_kernel<<<512, 256, 0, stream>>>(dst, bkt_cnt, E, SE, NB, NBS);
        bucket_scan_kernel<<<1, 1024, 0, stream>>>(bkt_cnt, bkt_off, bkt_cur, NBS);
        bucket_scatter_kernel<<<512, 256, 0, stream>>>(src, dst, bkt_cur, recs,
                                                       E, SE, NB, NBS);
        node_count_bucket_kernel<<<NBS, 256, 0, stream>>>(recs, bkt_off, cnt, N, NB);
        partial_kernel<<<dim3(BPS, S), 256, 0, stream>>>(cnt, partials, N, BPS);
        scan_partials_kernel<<<1, 1024, 0, stream>>>(partials, scanned, row_off,
                                                     S, BPS, N);
        emit_kernel<<<dim3(BPS, S), 256, 0, stream>>>(cnt, scanned, row_off, N, BPS);
        csr_fill_bucket_kernel<<<NBS, 256, 0, stream>>>(recs, bkt_off, row_off,
                                                        src_csr, N, E, NB);
    } else {
        hipMemsetAsync(cnt, 0, (size_t)S * N * sizeof(int), stream);
        count_all_kernel<<<se_blocks, 256, 0, stream>>>(dst, cnt, E, SE, N);
        partial_kernel<<<dim3(BPS, S), 256, 0, stream>>>(cnt, partials, N, BPS);
        scan_partials_kernel<<<1, 1024, 0, stream>>>(partials, scanned, row_off,
                                                     S, BPS, N);
        emit_kernel<<<dim3(BPS, S), 256, 0, stream>>>(cnt, scanned, row_off, N, BPS);
        emit_cursor_kernel<<<dim3(BPS, S), 256, 0, stream>>>(row_off, cnt, N);
        fill_all_kernel<<<se_blocks, 256, 0, stream>>>(src, dst, cnt, src_csr,
                                                       E, SE, N);
    }

    for (int k0 = 0; k0 < S; k0 += B) {
        proj_mfma_kernel<<<dim3(proj_blocks, B), 256, 0, stream>>>(
            (const unsigned short*)feat16, Wt, bvec, a8, bp16, N, k0);
        fused_kernel<<<dim3(node_blocks, B), 256, 0, stream>>>(
            (const uint4*)feat16, (const uint2*)a8, (const uint4*)bp16, wout,
            src_csr, row_off, out, N, S, E, k0);
    }
}